// Round 5
// baseline (11903.836 us; speedup 1.0000x reference)
//
#include <hip/hip_runtime.h>

#define B_SZ   256
#define DIN    128
#define T_LEN  2000
#define K_SZ   64
#define NTILE  32          // 32 tiles of 64 t cover 2048 >= 2000
#define ISTR   68          // I row stride (floats), [k][t] layout: aligned b128 reads, free 2-way banks

typedef float f32x4 __attribute__((ext_vector_type(4)));   // native vec for nontemporal builtins

// ---- 32 x-values (one d-group) into registers, fully unrolled (static reg indices) ----
__device__ __forceinline__ void load32(const float* __restrict__ xp, int g, float (&r)[32]) {
#pragma unroll
  for (int j = 0; j < 32; ++j)
    r[j] = xp[(size_t)(g * 32 + j) * T_LEN];
}

// ---- 32 d-steps x 16 k FMAs; W broadcast from LDS (wave-uniform b128 reads) ----
__device__ __forceinline__ void fma32(const float (&r)[32], float (&acc)[16],
                                      const float* __restrict__ Wt, int g, int k0) {
#pragma unroll
  for (int j = 0; j < 32; ++j) {
    const int d = g * 32 + j;
    const float4 w0 = *(const float4*)&Wt[d * K_SZ + k0 + 0];
    const float4 w1 = *(const float4*)&Wt[d * K_SZ + k0 + 4];
    const float4 w2 = *(const float4*)&Wt[d * K_SZ + k0 + 8];
    const float4 w3 = *(const float4*)&Wt[d * K_SZ + k0 + 12];
    const float xv = r[j];
    acc[0]  = fmaf(w0.x, xv, acc[0]);  acc[1]  = fmaf(w0.y, xv, acc[1]);
    acc[2]  = fmaf(w0.z, xv, acc[2]);  acc[3]  = fmaf(w0.w, xv, acc[3]);
    acc[4]  = fmaf(w1.x, xv, acc[4]);  acc[5]  = fmaf(w1.y, xv, acc[5]);
    acc[6]  = fmaf(w1.z, xv, acc[6]);  acc[7]  = fmaf(w1.w, xv, acc[7]);
    acc[8]  = fmaf(w2.x, xv, acc[8]);  acc[9]  = fmaf(w2.y, xv, acc[9]);
    acc[10] = fmaf(w2.z, xv, acc[10]); acc[11] = fmaf(w2.w, xv, acc[11]);
    acc[12] = fmaf(w3.x, xv, acc[12]); acc[13] = fmaf(w3.y, xv, acc[13]);
    acc[14] = fmaf(w3.z, xv, acc[14]); acc[15] = fmaf(w3.w, xv, acc[15]);
  }
}

// ---- write this wave's 16 k-rows of the I tile (lane = t column; lane-stride-1 -> conflict-free) ----
__device__ __forceinline__ void writeI(float* Iw, const float (&acc)[16], int k0, int lane) {
#pragma unroll
  for (int kk = 0; kk < 16; ++kk)
    Iw[(k0 + kk) * ISTR + lane] = acc[kk];
}

// ---- 16 sequential LIF steps; all 64 lanes compute (branch-free chain), lanes<16 store ----
__device__ __forceinline__ void scan16(const float* __restrict__ Ir, int tt0, int tg,
                                       float bias_s, float alpha, float vth_s,
                                       float& V, float* __restrict__ outS,
                                       float* __restrict__ outV, int sk, bool active)
{
  const float4 i0 = *(const float4*)&Ir[tt0 + 0];
  const float4 i1 = *(const float4*)&Ir[tt0 + 4];
  const float4 i2 = *(const float4*)&Ir[tt0 + 8];
  const float4 i3 = *(const float4*)&Ir[tt0 + 12];
  float Iv[16] = { i0.x, i0.y, i0.z, i0.w,  i1.x, i1.y, i1.z, i1.w,
                   i2.x, i2.y, i2.z, i2.w,  i3.x, i3.y, i3.z, i3.w };
  float S[16], Vv[16];
#pragma unroll
  for (int t = 0; t < 16; ++t) {
    const float Vp = fmaf(alpha, V, Iv[t] + bias_s);  // bias-add is off-chain
    const bool  sp = Vp > vth_s;
    V = sp ? (Vp - vth_s) : Vp;
    S[t]  = sp ? 1.0f : 0.0f;
    Vv[t] = V;
  }
  if (active) {
    float* ps = &outS[(size_t)sk * T_LEN + tg];
    float* pv = &outV[(size_t)sk * T_LEN + tg];
#pragma unroll
    for (int q = 0; q < 4; ++q) {
      f32x4 vs = { S[4*q], S[4*q+1], S[4*q+2], S[4*q+3] };
      f32x4 vv = { Vv[4*q], Vv[4*q+1], Vv[4*q+2], Vv[4*q+3] };
      __builtin_nontemporal_store(vs, (f32x4*)&ps[4*q]);
      __builtin_nontemporal_store(vv, (f32x4*)&pv[4*q]);
    }
  }
}

__global__ __launch_bounds__(256, 1)
void lif_fused(const float* __restrict__ x,
               const float* __restrict__ W,
               const float* __restrict__ bias,
               const float* __restrict__ vth,
               const float* __restrict__ tau,
               float* __restrict__ out)
{
  __shared__ __align__(16) float Wt[DIN * K_SZ];          // 32 KB, Wt[d*64 + k]
  __shared__ __align__(16) float Ibuf[2][K_SZ * ISTR];    // 2 x 17 KB, I[k][t] per tile (wave-private k-rows)

  const int tid  = threadIdx.x;
  const int b    = blockIdx.x;
  const int wave = tid >> 6;
  const int lane = tid & 63;
  const int k0   = wave << 4;               // 16 k's per wave

  // W[k][d] (coalesced global) -> Wt[d][k]; one-time, conflicts negligible
  for (int idx = tid; idx < DIN * K_SZ; idx += 256) {
    const int k = idx >> 7;
    const int d = idx & 127;
    Wt[d * K_SZ + k] = W[idx];
  }

  const int   sk     = k0 + (lane & 15);    // scan k owned by this lane (4x redundant across lane groups)
  const float alpha  = expf(-1.0f / tau[sk]);
  const float vth_s  = vth[sk];
  const float bias_s = bias[sk];

  const float* xb   = x + (size_t)b * (DIN * T_LEN);
  float*       outS = out + (size_t)b * (K_SZ * T_LEN);
  float*       outV = outS + (size_t)B_SZ * K_SZ * T_LEN;

  __syncthreads();   // the ONLY barrier: Wt ready. I-tile is wave-private -> no in-loop syncs.

  auto xptr = [&](int tile) -> const float* {
    int tcol = tile * 64 + lane;
    if (tcol > T_LEN - 1) tcol = T_LEN - 1;   // clamped columns are never consumed
    return xb + tcol;
  };

  float V = 0.0f;
  float A[32], Bx[32], acc[16];

  // ---------------- prologue: GEMM tile 0 (no scan yet) ----------------
  {
    const float* xp = xptr(0);
    load32(xp, 0, A);
    load32(xp, 1, Bx);
#pragma unroll
    for (int i = 0; i < 16; ++i) acc[i] = 0.0f;
    fma32(A,  acc, Wt, 0, k0);
    load32(xp, 2, A);
    fma32(Bx, acc, Wt, 1, k0);
    load32(xp, 3, Bx);
    fma32(A,  acc, Wt, 2, k0);
    fma32(Bx, acc, Wt, 3, k0);
    writeI(Ibuf[0], acc, k0, lane);
    const float* xn = xptr(1);               // prefetch tile 1 (full-tile latency cover)
    load32(xn, 0, A);
    load32(xn, 1, Bx);
  }

  // ---------------- main loop: GEMM(tile) || scan(tile-1) ----------------
#pragma unroll 1
  for (int tile = 1; tile < NTILE; ++tile) {
    float*       Iw = Ibuf[tile & 1];
    const float* Ir = Ibuf[(tile - 1) & 1] + (size_t)sk * ISTR;
    const int   tp0 = (tile - 1) * 64;
    const float* xp = xptr(tile);

#pragma unroll
    for (int i = 0; i < 16; ++i) acc[i] = 0.0f;

    fma32(A,  acc, Wt, 0, k0);
    load32(xp, 2, A);
    scan16(Ir,  0, tp0 +  0, bias_s, alpha, vth_s, V, outS, outV, sk, lane < 16);
    fma32(Bx, acc, Wt, 1, k0);
    load32(xp, 3, Bx);
    scan16(Ir, 16, tp0 + 16, bias_s, alpha, vth_s, V, outS, outV, sk, lane < 16);
    fma32(A,  acc, Wt, 2, k0);
    scan16(Ir, 32, tp0 + 32, bias_s, alpha, vth_s, V, outS, outV, sk, lane < 16);
    fma32(Bx, acc, Wt, 3, k0);
    scan16(Ir, 48, tp0 + 48, bias_s, alpha, vth_s, V, outS, outV, sk, lane < 16);
    writeI(Iw, acc, k0, lane);

    const float* xn = xptr(tile + 1);        // tile 32 -> clamped, harmless; keeps loop branch-free
    load32(xn, 0, A);
    load32(xn, 1, Bx);
  }

  // ---------------- epilogue: scan tail of tile 31 (t = 1984..1999) ----------------
  {
    const float* Ir = Ibuf[(NTILE - 1) & 1] + (size_t)sk * ISTR;
    scan16(Ir, 0, (NTILE - 1) * 64, bias_s, alpha, vth_s, V, outS, outV, sk, lane < 16);
  }
}

extern "C" void kernel_launch(void* const* d_in, const int* in_sizes, int n_in,
                              void* d_out, int out_size, void* d_ws, size_t ws_size,
                              hipStream_t stream) {
  const float* x    = (const float*)d_in[0];
  const float* W    = (const float*)d_in[1];
  const float* bias = (const float*)d_in[2];
  const float* vth  = (const float*)d_in[3];
  const float* tau  = (const float*)d_in[4];
  float* out        = (float*)d_out;

  lif_fused<<<dim3(B_SZ), dim3(256), 0, stream>>>(x, W, bias, vth, tau, out);
}

// Round 6
// 10698.672 us; speedup vs baseline: 1.1126x; 1.1126x over previous
//
#include <hip/hip_runtime.h>

#define B_SZ   256
#define DIN    128
#define T_LEN  2000
#define K_SZ   64
#define TT     64
#define NTILE  32
#define ISTR   68          // I row stride (floats); sk*68*4 B = 272*sk -> 16B-aligned float4 reads

// ---- per-wave x stage: 8 float4 loads; wave w owns d-rows [32w, 32w+32) ----
// lane mapping: row = 32w + 4q + (lane>>4), col = (lane&15)*4  -> 256B coalesced per row
__device__ __forceinline__ void stage_load(const float* __restrict__ xl, float4 (&st)[8]) {
#pragma unroll
  for (int q = 0; q < 8; ++q)
    st[q] = *(const float4*)(xl + (size_t)q * 4 * T_LEN);
}

__device__ __forceinline__ void stage_write(float* __restrict__ Xb, const float4 (&st)[8],
                                            int wave, int lane) {
  float* base = Xb + (wave * 32 + (lane >> 4)) * TT + (lane & 15) * 4;
#pragma unroll
  for (int q = 0; q < 8; ++q)
    *(float4*)(base + q * 4 * TT) = st[q];   // contiguous 1KB per instr -> no bank conflicts
}

// ---- 32 d-steps: acc[k] += x[d][t=lane] * W[k][d]; W via wave-uniform b128 broadcast ----
__device__ __forceinline__ void gemm32(const float* __restrict__ Xb, int d0,
                                       float (&acc)[16], const float* __restrict__ Wt,
                                       int k0, int lane) {
#pragma unroll
  for (int j = 0; j < 32; ++j) {
    const int d = d0 + j;
    const float xv = Xb[d * TT + lane];                       // ds_read_b32, 2-way (free)
    const float4 w0 = *(const float4*)&Wt[d * K_SZ + k0 + 0]; // broadcast
    const float4 w1 = *(const float4*)&Wt[d * K_SZ + k0 + 4];
    const float4 w2 = *(const float4*)&Wt[d * K_SZ + k0 + 8];
    const float4 w3 = *(const float4*)&Wt[d * K_SZ + k0 + 12];
    acc[0]  = fmaf(w0.x, xv, acc[0]);  acc[1]  = fmaf(w0.y, xv, acc[1]);
    acc[2]  = fmaf(w0.z, xv, acc[2]);  acc[3]  = fmaf(w0.w, xv, acc[3]);
    acc[4]  = fmaf(w1.x, xv, acc[4]);  acc[5]  = fmaf(w1.y, xv, acc[5]);
    acc[6]  = fmaf(w1.z, xv, acc[6]);  acc[7]  = fmaf(w1.w, xv, acc[7]);
    acc[8]  = fmaf(w2.x, xv, acc[8]);  acc[9]  = fmaf(w2.y, xv, acc[9]);
    acc[10] = fmaf(w2.z, xv, acc[10]); acc[11] = fmaf(w2.w, xv, acc[11]);
    acc[12] = fmaf(w3.x, xv, acc[12]); acc[13] = fmaf(w3.y, xv, acc[13]);
    acc[14] = fmaf(w3.z, xv, acc[14]); acc[15] = fmaf(w3.w, xv, acc[15]);
  }
}

__device__ __forceinline__ void writeI(float* __restrict__ Iw, const float (&acc)[16],
                                       int k0, int lane) {
#pragma unroll
  for (int kk = 0; kk < 16; ++kk)
    Iw[(k0 + kk) * ISTR + lane] = acc[kk];   // lane-stride-1 -> conflict-free
}

// ---- 16 sequential LIF steps; all 64 lanes compute (branch-free), lanes<16 store ----
__device__ __forceinline__ void scan16(const float* __restrict__ Ir, int c0, int tg,
                                       float bias_s, float alpha, float vth_s,
                                       float& V, float* __restrict__ outS,
                                       float* __restrict__ outV, int sk, bool active)
{
  const float4 i0 = *(const float4*)&Ir[c0 + 0];
  const float4 i1 = *(const float4*)&Ir[c0 + 4];
  const float4 i2 = *(const float4*)&Ir[c0 + 8];
  const float4 i3 = *(const float4*)&Ir[c0 + 12];
  float Iv[16] = { i0.x, i0.y, i0.z, i0.w,  i1.x, i1.y, i1.z, i1.w,
                   i2.x, i2.y, i2.z, i2.w,  i3.x, i3.y, i3.z, i3.w };
  float S[16], Vv[16];
#pragma unroll
  for (int t = 0; t < 16; ++t) {
    const float Vp = fmaf(alpha, V, Iv[t] + bias_s);
    const bool  sp = Vp > vth_s;
    V = sp ? (Vp - vth_s) : Vp;
    S[t]  = sp ? 1.0f : 0.0f;
    Vv[t] = V;
  }
  if (active) {
    float* ps = &outS[(size_t)sk * T_LEN + tg];
    float* pv = &outV[(size_t)sk * T_LEN + tg];
#pragma unroll
    for (int q = 0; q < 4; ++q) {
      *(float4*)&ps[4*q] = make_float4(S[4*q],  S[4*q+1],  S[4*q+2],  S[4*q+3]);
      *(float4*)&pv[4*q] = make_float4(Vv[4*q], Vv[4*q+1], Vv[4*q+2], Vv[4*q+3]);
    }
  }
}

__global__ __launch_bounds__(256, 1)
void lif_fused(const float* __restrict__ x,
               const float* __restrict__ W,
               const float* __restrict__ bias,
               const float* __restrict__ vth,
               const float* __restrict__ tau,
               float* __restrict__ out)
{
  __shared__ __align__(16) float Wt[DIN * K_SZ];        // 32 KB  [d][k]
  __shared__ __align__(16) float Xt[2][DIN * TT];       // 64 KB  [d][t] double-buffered
  __shared__ __align__(16) float Ibuf[2][K_SZ * ISTR];  // 34 KB  [k][t] double-buffered

  const int tid  = threadIdx.x;
  const int b    = blockIdx.x;
  const int wave = tid >> 6;
  const int lane = tid & 63;
  const int k0   = wave << 4;

  // W[k][d] (coalesced global read) -> Wt[d][k]; one-time
  for (int idx = tid; idx < DIN * K_SZ; idx += 256) {
    const int k = idx >> 7;
    const int d = idx & 127;
    Wt[d * K_SZ + k] = W[idx];
  }

  const int   sk     = k0 + (lane & 15);
  const float alpha  = expf(-1.0f / tau[sk]);
  const float vth_s  = vth[sk];
  const float bias_s = bias[sk];

  const float* xb   = x + (size_t)b * (DIN * T_LEN);
  float*       outS = out + (size_t)b * (K_SZ * T_LEN);
  float*       outV = outS + (size_t)B_SZ * K_SZ * T_LEN;

  // per-lane global stage base: row = 32*wave + (lane>>4), col = (lane&15)*4
  const float* xl = xb + (size_t)(32 * wave + (lane >> 4)) * T_LEN + (lane & 15) * 4;

  const bool active = (lane < 16);
  float V = 0.0f;
  float acc[16];
  float4 st[8];

  // ---------------- prologue: stage tile 0, barrier (also covers Wt) ----------------
  stage_load(xl + 0, st);
  stage_write(Xt[0], st, wave, lane);
  __syncthreads();

  // ---------------- tile 0: GEMM only (no scan yet) ----------------
  {
    stage_load(xl + 64, st);                  // tile 1
#pragma unroll
    for (int i = 0; i < 16; ++i) acc[i] = 0.0f;
    gemm32(Xt[0],  0, acc, Wt, k0, lane);
    gemm32(Xt[0], 32, acc, Wt, k0, lane);
    stage_write(Xt[1], st, wave, lane);       // ~2000 cyc after issue -> latency covered
    gemm32(Xt[0], 64, acc, Wt, k0, lane);
    gemm32(Xt[0], 96, acc, Wt, k0, lane);
    writeI(Ibuf[0], acc, k0, lane);
    __syncthreads();
  }

  // ---------------- tiles 1..30: GEMM(tile) || scan(tile-1) ----------------
#pragma unroll 1
  for (int tile = 1; tile <= 30; ++tile) {
    const int cur = tile & 1;
    const float* Xc = Xt[cur];
    float*       Xn = Xt[cur ^ 1];
    float*       Iw = Ibuf[cur];
    const float* Ir = Ibuf[cur ^ 1] + (size_t)sk * ISTR;
    const int   tp0 = (tile - 1) * 64;
    const int  st0n = (tile + 1 == NTILE - 1) ? (T_LEN - TT) : (tile + 1) * 64;  // last tile clamped in-bounds

    stage_load(xl + st0n, st);                // issue next-tile loads early
#pragma unroll
    for (int i = 0; i < 16; ++i) acc[i] = 0.0f;

    gemm32(Xc,  0, acc, Wt, k0, lane);
    scan16(Ir,  0, tp0 +  0, bias_s, alpha, vth_s, V, outS, outV, sk, active);
    gemm32(Xc, 32, acc, Wt, k0, lane);
    scan16(Ir, 16, tp0 + 16, bias_s, alpha, vth_s, V, outS, outV, sk, active);
    stage_write(Xn, st, wave, lane);          // vmcnt wait lands here, loads long since done
    gemm32(Xc, 64, acc, Wt, k0, lane);
    scan16(Ir, 32, tp0 + 32, bias_s, alpha, vth_s, V, outS, outV, sk, active);
    gemm32(Xc, 96, acc, Wt, k0, lane);
    scan16(Ir, 48, tp0 + 48, bias_s, alpha, vth_s, V, outS, outV, sk, active);
    writeI(Iw, acc, k0, lane);
    __syncthreads();
  }

  // ---------------- tile 31 (staged from t0=1936; cols 48..63 = t 1984..1999) ----------------
  {
    const float* Xc = Xt[1];                  // 31 & 1
    const float* Ir = Ibuf[0] + (size_t)sk * ISTR;
    const int   tp0 = 30 * 64;                // scan tile 30: t 1920..1983
#pragma unroll
    for (int i = 0; i < 16; ++i) acc[i] = 0.0f;
    gemm32(Xc,  0, acc, Wt, k0, lane);
    scan16(Ir,  0, tp0 +  0, bias_s, alpha, vth_s, V, outS, outV, sk, active);
    gemm32(Xc, 32, acc, Wt, k0, lane);
    scan16(Ir, 16, tp0 + 16, bias_s, alpha, vth_s, V, outS, outV, sk, active);
    gemm32(Xc, 64, acc, Wt, k0, lane);
    scan16(Ir, 32, tp0 + 32, bias_s, alpha, vth_s, V, outS, outV, sk, active);
    gemm32(Xc, 96, acc, Wt, k0, lane);
    scan16(Ir, 48, tp0 + 48, bias_s, alpha, vth_s, V, outS, outV, sk, active);
    writeI(Ibuf[1], acc, k0, lane);           // same-wave LDS write->read, no barrier needed
  }

  // ---------------- epilogue: t 1984..1999 at I-tile cols 48..63 ----------------
  {
    const float* Ir = Ibuf[1] + (size_t)sk * ISTR;
    scan16(Ir, 48, 1984, bias_s, alpha, vth_s, V, outS, outV, sk, active);
  }
}

extern "C" void kernel_launch(void* const* d_in, const int* in_sizes, int n_in,
                              void* d_out, int out_size, void* d_ws, size_t ws_size,
                              hipStream_t stream) {
  const float* x    = (const float*)d_in[0];
  const float* W    = (const float*)d_in[1];
  const float* bias = (const float*)d_in[2];
  const float* vth  = (const float*)d_in[3];
  const float* tau  = (const float*)d_in[4];
  float* out        = (float*)d_out;

  lif_fused<<<dim3(B_SZ), dim3(256), 0, stream>>>(x, W, bias, vth, tau, out);
}

// Round 9
// 593.589 us; speedup vs baseline: 20.0540x; 18.0237x over previous
//
#include <hip/hip_runtime.h>

#define B_SZ   256
#define DIN    128
#define T_LEN  2000
#define K_SZ   64
#define TT     64
#define NTILE  32
#define ISTR   68   // I row stride (floats): rows 272B apart -> float4-aligned, 2-way banks on scan reads (free)

// ---- x staging: wave w owns d-rows [32w,32w+32); lane l: row 32w+4q+(l>>4), col 4*(l&15) ----
__device__ __forceinline__ void stage_load(const float* __restrict__ xl, float4 (&st)[8]) {
#pragma unroll
  for (int q = 0; q < 8; ++q)
    st[q] = *(const float4*)(xl + (size_t)q * 4 * T_LEN);
}

__device__ __forceinline__ void stage_write(float* __restrict__ Xb, const float4 (&st)[8],
                                            int wave, int lane) {
  float* base = Xb + (wave * 32 + (lane >> 4)) * TT + (lane & 15) * 4;
#pragma unroll
  for (int q = 0; q < 8; ++q)
    *(float4*)(base + q * 4 * TT) = st[q];
}

// ---- GEMM: thread (i,j) accumulates I[4i..4i+4][4j..4j+4]; 2 b128 LDS reads per d-step ----
__device__ __forceinline__ void gemm_range(const float* __restrict__ Xb,
                                           const float* __restrict__ Wt,
                                           int d0, int d1, int i4, int j4,
                                           float (&acc)[16]) {
#pragma unroll 4
  for (int d = d0; d < d1; ++d) {
    const float4 w4 = *(const float4*)&Wt[d * K_SZ + i4];   // 4 k's (16-lane broadcast groups)
    const float4 x4 = *(const float4*)&Xb[d * TT + j4];     // 4 t's (4-lane broadcast groups)
    acc[0]  = fmaf(w4.x, x4.x, acc[0]);  acc[1]  = fmaf(w4.x, x4.y, acc[1]);
    acc[2]  = fmaf(w4.x, x4.z, acc[2]);  acc[3]  = fmaf(w4.x, x4.w, acc[3]);
    acc[4]  = fmaf(w4.y, x4.x, acc[4]);  acc[5]  = fmaf(w4.y, x4.y, acc[5]);
    acc[6]  = fmaf(w4.y, x4.z, acc[6]);  acc[7]  = fmaf(w4.y, x4.w, acc[7]);
    acc[8]  = fmaf(w4.z, x4.x, acc[8]);  acc[9]  = fmaf(w4.z, x4.y, acc[9]);
    acc[10] = fmaf(w4.z, x4.z, acc[10]); acc[11] = fmaf(w4.z, x4.w, acc[11]);
    acc[12] = fmaf(w4.w, x4.x, acc[12]); acc[13] = fmaf(w4.w, x4.y, acc[13]);
    acc[14] = fmaf(w4.w, x4.z, acc[14]); acc[15] = fmaf(w4.w, x4.w, acc[15]);
  }
}

__device__ __forceinline__ void writeI(float* __restrict__ Iw, const float (&acc)[16],
                                       int i4, int j4) {
#pragma unroll
  for (int mi = 0; mi < 4; ++mi)
    *(float4*)&Iw[(i4 + mi) * ISTR + j4] =
        make_float4(acc[4*mi], acc[4*mi+1], acc[4*mi+2], acc[4*mi+3]);
}

// ---- 16 LIF steps in 4-step chunks (small transients); all lanes compute, lanes<16 store ----
__device__ __forceinline__ void scan16(const float* __restrict__ Ir, int c0, int tg,
                                       float bias_s, float alpha, float vth_s,
                                       float& V, float* __restrict__ outS,
                                       float* __restrict__ outV, int sk, bool active)
{
#pragma unroll
  for (int q = 0; q < 4; ++q) {
    const float4 iv = *(const float4*)&Ir[c0 + 4*q];
    float S0,S1,S2,S3, V0,V1,V2,V3;
    { const float Vp = fmaf(alpha, V, iv.x + bias_s); const bool sp = Vp > vth_s;
      V0 = sp ? (Vp - vth_s) : Vp; S0 = sp ? 1.0f : 0.0f; V = V0; }
    { const float Vp = fmaf(alpha, V, iv.y + bias_s); const bool sp = Vp > vth_s;
      V1 = sp ? (Vp - vth_s) : Vp; S1 = sp ? 1.0f : 0.0f; V = V1; }
    { const float Vp = fmaf(alpha, V, iv.z + bias_s); const bool sp = Vp > vth_s;
      V2 = sp ? (Vp - vth_s) : Vp; S2 = sp ? 1.0f : 0.0f; V = V2; }
    { const float Vp = fmaf(alpha, V, iv.w + bias_s); const bool sp = Vp > vth_s;
      V3 = sp ? (Vp - vth_s) : Vp; S3 = sp ? 1.0f : 0.0f; V = V3; }
    if (active) {
      *(float4*)&outS[(size_t)sk * T_LEN + tg + 4*q] = make_float4(S0, S1, S2, S3);
      *(float4*)&outV[(size_t)sk * T_LEN + tg + 4*q] = make_float4(V0, V1, V2, V3);
    }
  }
}

__global__ __launch_bounds__(256, 1)
void lif_fused(const float* __restrict__ x,
               const float* __restrict__ W,
               const float* __restrict__ bias,
               const float* __restrict__ vth,
               const float* __restrict__ tau,
               float* __restrict__ out)
{
  __shared__ __align__(16) float Wt[DIN * K_SZ];        // 32 KB [d][k]
  __shared__ __align__(16) float Xt[2][DIN * TT];       // 64 KB [d][t] x2
  __shared__ __align__(16) float Ibuf[2][K_SZ * ISTR];  // 34 KB [k][t] x2

  const int tid  = threadIdx.x;
  const int b    = blockIdx.x;
  const int wave = tid >> 6;
  const int lane = tid & 63;
  const int i4   = (tid >> 4) << 2;   // k-base of this thread's 4x4 tile
  const int j4   = (tid & 15) << 2;   // t-base

  // W[k][d] (coalesced read) -> Wt[d][k]; one-time
  for (int idx = tid; idx < DIN * K_SZ; idx += 256) {
    const int k = idx >> 7;
    const int d = idx & 127;
    Wt[d * K_SZ + k] = W[idx];
  }

  const int   sk     = (wave << 4) + (lane & 15);   // scan k (wave-local rows; 4x redundant groups)
  const float alpha  = expf(-1.0f / tau[sk]);
  const float vth_s  = vth[sk];
  const float bias_s = bias[sk];

  const float* xb   = x + (size_t)b * (DIN * T_LEN);
  float*       outS = out + (size_t)b * (K_SZ * T_LEN);
  float*       outV = outS + (size_t)B_SZ * K_SZ * T_LEN;

  const float* xl = xb + (size_t)(32 * wave + (lane >> 4)) * T_LEN + (lane & 15) * 4;

  const bool active = (lane < 16);
  float V = 0.0f;
  float acc[16];
  float4 st[8];

  // ---------------- prologue: stage tile 0 ----------------
  stage_load(xl + 0, st);
  stage_write(Xt[0], st, wave, lane);
  __syncthreads();                       // covers Wt + Xt[0]

  // ---------------- tile 0: GEMM only ----------------
  {
    stage_load(xl + 64, st);             // tile 1
#pragma unroll
    for (int i = 0; i < 16; ++i) acc[i] = 0.0f;
    gemm_range(Xt[0], Wt, 0, 64, i4, j4, acc);
    stage_write(Xt[1], st, wave, lane);  // vmcnt drain covered by first gemm half
    gemm_range(Xt[0], Wt, 64, 128, i4, j4, acc);
    writeI(Ibuf[0], acc, i4, j4);
    __syncthreads();
  }

  // ---------------- tiles 1..30: GEMM(tile) || scan(tile-1) ----------------
#pragma unroll 1
  for (int tile = 1; tile <= 30; ++tile) {
    const int cur = tile & 1;
    const float* Xc = Xt[cur];
    float*       Xn = Xt[cur ^ 1];
    float*       Iw = Ibuf[cur];
    const float* Ir = Ibuf[cur ^ 1] + (size_t)sk * ISTR;
    const int   tp0 = (tile - 1) * 64;
    const int  st0n = (tile + 1 == NTILE - 1) ? (T_LEN - TT) : (tile + 1) * 64;

    stage_load(xl + st0n, st);
#pragma unroll
    for (int i = 0; i < 16; ++i) acc[i] = 0.0f;

    gemm_range(Xc, Wt, 0, 64, i4, j4, acc);
    scan16(Ir,  0, tp0 +  0, bias_s, alpha, vth_s, V, outS, outV, sk, active);
    scan16(Ir, 16, tp0 + 16, bias_s, alpha, vth_s, V, outS, outV, sk, active);
    stage_write(Xn, st, wave, lane);
    gemm_range(Xc, Wt, 64, 128, i4, j4, acc);
    scan16(Ir, 32, tp0 + 32, bias_s, alpha, vth_s, V, outS, outV, sk, active);
    scan16(Ir, 48, tp0 + 48, bias_s, alpha, vth_s, V, outS, outV, sk, active);
    writeI(Iw, acc, i4, j4);
    __syncthreads();
  }

  // ---------------- tile 31 (staged from t0=1936; cols 48..63 = t 1984..1999) ----------------
  {
    const float* Xc = Xt[1];
    const float* Ir = Ibuf[0] + (size_t)sk * ISTR;
    const int   tp0 = 30 * 64;
#pragma unroll
    for (int i = 0; i < 16; ++i) acc[i] = 0.0f;
    gemm_range(Xc, Wt, 0, 64, i4, j4, acc);
    scan16(Ir,  0, tp0 +  0, bias_s, alpha, vth_s, V, outS, outV, sk, active);
    scan16(Ir, 16, tp0 + 16, bias_s, alpha, vth_s, V, outS, outV, sk, active);
    gemm_range(Xc, Wt, 64, 128, i4, j4, acc);
    scan16(Ir, 32, tp0 + 32, bias_s, alpha, vth_s, V, outS, outV, sk, active);
    scan16(Ir, 48, tp0 + 48, bias_s, alpha, vth_s, V, outS, outV, sk, active);
    writeI(Ibuf[1], acc, i4, j4);
    // same-wave LDS write->read below (lgkmcnt handled by compiler); rows are wave-local
  }

  // ---------------- epilogue: t 1984..1999 ----------------
  {
    const float* Ir = Ibuf[1] + (size_t)sk * ISTR;
    scan16(Ir, 48, 1984, bias_s, alpha, vth_s, V, outS, outV, sk, active);
  }
}

extern "C" void kernel_launch(void* const* d_in, const int* in_sizes, int n_in,
                              void* d_out, int out_size, void* d_ws, size_t ws_size,
                              hipStream_t stream) {
  const float* x    = (const float*)d_in[0];
  const float* W    = (const float*)d_in[1];
  const float* bias = (const float*)d_in[2];
  const float* vth  = (const float*)d_in[3];
  const float* tau  = (const float*)d_in[4];
  float* out        = (float*)d_out;

  lif_fused<<<dim3(B_SZ), dim3(256), 0, stream>>>(x, W, bias, vth, tau, out);
}